// Round 6
// baseline (70.046 us; speedup 1.0000x reference)
//
#include <hip/hip_runtime.h>
#include <stdint.h>

// pooled[b,o] = x[b,:] . Wp[o,:] + biasp[o] + 0.25*(y[b,n0]+y[b,n0+1]+y[b,n0+64]+y[b,n0+65])
//   o = p*32+q, n0 = 128p+2q; Wp = 2x2-pooled W rows. out = pooled / mean(pooled).
// 3 dispatches: prep (x->bf16, pool W/bias) -> gemm (128x128, dbuf LDS, phase-
// split K-loop with counted vmcnt spanning barriers, setprio MFMA clusters,
// pipelined y epilogue) -> norm (redundant 512-partial reduce + scale).

#define KDIM 1024
#define NP   1024
#define BM 128
#define BN 128
#define BK 64

typedef __bf16 bf16x8 __attribute__((ext_vector_type(8)));
typedef float f32x4 __attribute__((ext_vector_type(4)));

__device__ __forceinline__ unsigned f2bf(float f) {
  union { float f; unsigned u; } v; v.f = f;
  unsigned r = v.u + 0x7fffu + ((v.u >> 16) & 1u);  // RNE
  return r >> 16;
}

__device__ __forceinline__ void gload_lds16(const void* g, void* l) {
  __builtin_amdgcn_global_load_lds(
      (const __attribute__((address_space(1))) void*)g,
      (__attribute__((address_space(3))) void*)l, 16, 0, 0);
}

// ---- kernel 1 (merged prep): x fp32->bf16 (blocks 0..4095), pool W+bias ----
__global__ void k_prep(const float* __restrict__ x, const float* __restrict__ W,
                       const float* __restrict__ bias,
                       unsigned short* __restrict__ xb, unsigned short* __restrict__ wp,
                       float* __restrict__ biasp) {
  int b = blockIdx.x;
  int t = threadIdx.x;
  if (b < 4096) {
    int i = b * 256 + t;  // 8 elems per thread
    const float4* x4 = (const float4*)x;
    float4 a = x4[i * 2], c = x4[i * 2 + 1];
    uint4 o;
    o.x = f2bf(a.x) | (f2bf(a.y) << 16);
    o.y = f2bf(a.z) | (f2bf(a.w) << 16);
    o.z = f2bf(c.x) | (f2bf(c.y) << 16);
    o.w = f2bf(c.z) | (f2bf(c.w) << 16);
    ((uint4*)xb)[i] = o;
  } else {
    int o = b - 4096;  // pooled feature index
    int r0 = ((o >> 5) << 7) + ((o & 31) << 1);
    const float4* W4 = (const float4*)W;
    float4 w0 = W4[(r0) * 256 + t];
    float4 w1 = W4[(r0 + 1) * 256 + t];
    float4 w2 = W4[(r0 + 64) * 256 + t];
    float4 w3 = W4[(r0 + 65) * 256 + t];
    float ax = 0.25f * (w0.x + w1.x + w2.x + w3.x);
    float ay = 0.25f * (w0.y + w1.y + w2.y + w3.y);
    float az = 0.25f * (w0.z + w1.z + w2.z + w3.z);
    float aw = 0.25f * (w0.w + w1.w + w2.w + w3.w);
    uint2 pk;
    pk.x = f2bf(ax) | (f2bf(ay) << 16);
    pk.y = f2bf(az) | (f2bf(aw) << 16);
    ((uint2*)wp)[o * 256 + t] = pk;
    if (t == 0)
      biasp[o] = 0.25f * (bias[r0] + bias[r0 + 1] + bias[r0 + 64] + bias[r0 + 65]);
  }
}

// ---- kernel 2: GEMM 8192x1024x1024 bf16 MFMA; phase-split dbuf pipeline ----
__global__ __launch_bounds__(256) void k_gemm(
    const unsigned short* __restrict__ xb, const unsigned short* __restrict__ wp,
    const float* __restrict__ biasp, const float* __restrict__ y,
    float* __restrict__ out, float* __restrict__ partials) {
  // buf in {0,1}: As(buf)=smem+buf*32768 (16KB), Bs(buf)=+16384
  __shared__ char smem[65536];

  int bid = blockIdx.x;
  // XCD swizzle: nwg=512 = 8*64, bijective
  int wg = (bid & 7) * 64 + (bid >> 3);
  int bm0 = (wg >> 3) * BM;
  int bn0 = (wg & 7) * BN;

  int tid = threadIdx.x;
  int lane = tid & 63;
  int wid = tid >> 6;
  int wr = wid >> 1, wc = wid & 1;  // wave tile 64x64

  f32x4 acc[4][4];
#pragma unroll
  for (int i = 0; i < 4; i++)
#pragma unroll
    for (int j = 0; j < 4; j++) acc[i][j] = (f32x4)0.0f;

  // staging: wave covers rows [wid*32, +32); LDS dest linear, SOURCE column
  // chunk pre-swizzled by (lane&7)^(lane>>3) (both-sides involution w/ read).
  int srow = wid * 32 + (lane >> 3);
  int scol = (((lane & 7) ^ (lane >> 3)) << 3);
  const unsigned short* aSrc = xb + (size_t)(bm0 + srow) * KDIM + scol;
  const unsigned short* bSrc = wp + (size_t)(bn0 + srow) * KDIM + scol;
  int ldsOff = wid * 4096;

  int rbase = (lane & 15) * 128;
  int xorv = (lane & 7) << 4;
  int cb0 = (((lane >> 4) * 16)) ^ xorv;
  int cb1 = ((64 + (lane >> 4) * 16)) ^ xorv;

#define STAGE_A(buf, ks)                                                       \
  {                                                                            \
    int k0 = (ks) * BK;                                                        \
    char* ab = smem + (buf) * 32768 + ldsOff;                                  \
    _Pragma("unroll")                                                          \
    for (int i = 0; i < 4; ++i)                                                \
      gload_lds16(aSrc + (size_t)i * 8 * KDIM + k0, ab + i * 1024);            \
  }
#define STAGE_B(buf, ks)                                                       \
  {                                                                            \
    int k0 = (ks) * BK;                                                        \
    char* bb = smem + (buf) * 32768 + 16384 + ldsOff;                          \
    _Pragma("unroll")                                                          \
    for (int i = 0; i < 4; ++i)                                                \
      gload_lds16(bSrc + (size_t)i * 8 * KDIM + k0, bb + i * 1024);            \
  }

  STAGE_A(0, 0);
  STAGE_B(0, 0);
  for (int ks = 0; ks < 16; ++ks) {
    int cur = ks & 1;
    // issue next tile's A half BEFORE the wait; counted vmcnt drains only the
    // current tile's 8, keeping 4 in flight across the barrier.
    if (ks < 15) {
      STAGE_A(cur ^ 1, ks + 1);
      asm volatile("s_waitcnt vmcnt(4)" ::: "memory");
    } else {
      asm volatile("s_waitcnt vmcnt(0)" ::: "memory");
    }
    __builtin_amdgcn_s_barrier();
    asm volatile("" ::: "memory");
    const char* Ab = smem + cur * 32768;
    const char* Bb = Ab + 16384;
    // phase 1: kk=0 cluster
    {
      bf16x8 af[4], bfr[4];
#pragma unroll
      for (int mi = 0; mi < 4; ++mi)
        af[mi] = *(const bf16x8*)(Ab + (wr * 64 + mi * 16) * 128 + rbase + cb0);
#pragma unroll
      for (int ni = 0; ni < 4; ++ni)
        bfr[ni] = *(const bf16x8*)(Bb + (wc * 64 + ni * 16) * 128 + rbase + cb0);
      __builtin_amdgcn_s_setprio(1);
#pragma unroll
      for (int mi = 0; mi < 4; ++mi)
#pragma unroll
        for (int ni = 0; ni < 4; ++ni)
          acc[mi][ni] = __builtin_amdgcn_mfma_f32_16x16x32_bf16(af[mi], bfr[ni], acc[mi][ni], 0, 0, 0);
      __builtin_amdgcn_s_setprio(0);
    }
    // issue next tile's B half between the MFMA clusters
    if (ks < 15) STAGE_B(cur ^ 1, ks + 1);
    // phase 2: kk=1 cluster
    {
      bf16x8 af[4], bfr[4];
#pragma unroll
      for (int mi = 0; mi < 4; ++mi)
        af[mi] = *(const bf16x8*)(Ab + (wr * 64 + mi * 16) * 128 + rbase + cb1);
#pragma unroll
      for (int ni = 0; ni < 4; ++ni)
        bfr[ni] = *(const bf16x8*)(Bb + (wc * 64 + ni * 16) * 128 + rbase + cb1);
      __builtin_amdgcn_s_setprio(1);
#pragma unroll
      for (int mi = 0; mi < 4; ++mi)
#pragma unroll
        for (int ni = 0; ni < 4; ++ni)
          acc[mi][ni] = __builtin_amdgcn_mfma_f32_16x16x32_bf16(af[mi], bfr[ni], acc[mi][ni], 0, 0, 0);
      __builtin_amdgcn_s_setprio(0);
    }
    asm volatile("" ::: "memory");
    __builtin_amdgcn_s_barrier();
  }

  // epilogue: software-pipelined y reads (double-buffered per (mi,ni) group,
  // all indices static after full unroll), add bias + pooled y, write raw out,
  // accumulate block sum.
  const float2* y2 = (const float2*)y;
  float tsum = 0.f;
  int r_l = (lane >> 4) * 4;
  int c_l = lane & 15;
  float2 pu[2][4], pv[2][4];

#define LOADG(buf, mi, ni)                                                     \
  {                                                                            \
    int col = bn0 + wc * 64 + (ni) * 16 + c_l;                                 \
    int yb = ((col >> 5) << 6) + (col & 31);                                   \
    _Pragma("unroll")                                                          \
    for (int j = 0; j < 4; ++j) {                                              \
      size_t row = (size_t)(bm0 + wr * 64 + (mi) * 16 + r_l + j);              \
      pu[buf][j] = y2[row * 2048 + yb];                                        \
      pv[buf][j] = y2[row * 2048 + yb + 32];                                   \
    }                                                                          \
  }
#define CONS(buf, mi, ni)                                                      \
  {                                                                            \
    int col = bn0 + wc * 64 + (ni) * 16 + c_l;                                 \
    float bp = biasp[col];                                                     \
    _Pragma("unroll")                                                          \
    for (int j = 0; j < 4; ++j) {                                              \
      int row = bm0 + wr * 64 + (mi) * 16 + r_l + j;                           \
      float val = acc[mi][ni][j] + bp +                                        \
                  0.25f * (pu[buf][j].x + pu[buf][j].y + pv[buf][j].x + pv[buf][j].y); \
      out[(size_t)row * NP + col] = val;                                       \
      tsum += val;                                                             \
    }                                                                          \
  }

  LOADG(0, 0, 0);
#pragma unroll
  for (int idx = 0; idx < 16; ++idx) {
    int mi = idx >> 2, ni = idx & 3;
    if (idx < 15) {
      int mi2 = (idx + 1) >> 2, ni2 = (idx + 1) & 3;
      LOADG((idx + 1) & 1, mi2, ni2);
    }
    CONS(idx & 1, mi, ni);
  }

#pragma unroll
  for (int off = 32; off > 0; off >>= 1) tsum += __shfl_down(tsum, off);
  float* sm = (float*)smem;
  __syncthreads();
  if (lane == 0) sm[wid] = tsum;
  __syncthreads();
  if (tid == 0) partials[bid] = (sm[0] + sm[1]) + (sm[2] + sm[3]);
}

// ---- kernel 3: redundant per-block reduce of 512 partials + scale out ----
__global__ void k_norm(float* __restrict__ out, const float* __restrict__ partials) {
  __shared__ float s[256];
  int t = threadIdx.x;
  s[t] = partials[t] + partials[t + 256];
  __syncthreads();
#pragma unroll
  for (int off = 128; off > 0; off >>= 1) {
    if (t < off) s[t] += s[t + off];
    __syncthreads();
  }
  float inv = 8388608.0f / s[0];  // (B*NP)/total
  int i = blockIdx.x * 256 + t;
  float4* o4 = (float4*)out;
  float4 v = o4[i];
  v.x *= inv; v.y *= inv; v.z *= inv; v.w *= inv;
  o4[i] = v;
}

extern "C" void kernel_launch(void* const* d_in, const int* in_sizes, int n_in,
                              void* d_out, int out_size, void* d_ws, size_t ws_size,
                              hipStream_t stream) {
  (void)in_sizes; (void)n_in; (void)out_size; (void)ws_size;
  const float* x = (const float*)d_in[0];
  const float* y = (const float*)d_in[1];
  const float* W = (const float*)d_in[2];
  const float* bias = (const float*)d_in[3];
  float* out = (float*)d_out;

  char* ws = (char*)d_ws;
  unsigned short* xb = (unsigned short*)(ws);                 // 16 MiB
  unsigned short* wp = (unsigned short*)(ws + 16777216);      // 2 MiB
  float* biasp = (float*)(ws + 16777216 + 2097152);           // 4 KiB
  float* partials = (float*)(ws + 16777216 + 2097152 + 4096); // 2 KiB

  hipLaunchKernelGGL(k_prep, dim3(5120), dim3(256), 0, stream, x, W, bias, xb, wp, biasp);
  hipLaunchKernelGGL(k_gemm, dim3(512), dim3(256), 0, stream, xb, wp, biasp, y, out, partials);
  hipLaunchKernelGGL(k_norm, dim3(8192), dim3(256), 0, stream, out, partials);
}

// Round 7
// 62.128 us; speedup vs baseline: 1.1275x; 1.1275x over previous
//
#include <hip/hip_runtime.h>
#include <stdint.h>

// pooled[b,o] = x[b,:] . Wp[o,:] + biasp[o] + 0.25*(y[b,n0]+y[b,n0+1]+y[b,n0+64]+y[b,n0+65])
//   o = p*32+q, n0 = 128p+2q; Wp = 2x2-pooled W rows. out = pooled / mean(pooled).
// 3 dispatches: prep (x->bf16, pool W/bias) -> gemm (128x128 tile, 8 waves =
// 16 waves/CU TLP, dbuf LDS, counted vmcnt, both-sides XOR swizzle; epilogue
// adds bias+pooled-y, writes f16 intermediate + block partials) -> norm
// (redundant deterministic 512-partial reduce; f16 -> scaled f32 out).

#define KDIM 1024
#define NP   1024
#define BM 128
#define BN 128
#define BK 64

typedef __bf16 bf16x8 __attribute__((ext_vector_type(8)));
typedef float f32x4 __attribute__((ext_vector_type(4)));
typedef _Float16 f16x4 __attribute__((ext_vector_type(4)));

__device__ __forceinline__ unsigned f2bf(float f) {
  union { float f; unsigned u; } v; v.f = f;
  unsigned r = v.u + 0x7fffu + ((v.u >> 16) & 1u);  // RNE
  return r >> 16;
}

__device__ __forceinline__ void gload_lds16(const void* g, void* l) {
  __builtin_amdgcn_global_load_lds(
      (const __attribute__((address_space(1))) void*)g,
      (__attribute__((address_space(3))) void*)l, 16, 0, 0);
}

// ---- kernel 1 (merged prep): x fp32->bf16 (blocks 0..4095), pool W+bias ----
__global__ void k_prep(const float* __restrict__ x, const float* __restrict__ W,
                       const float* __restrict__ bias,
                       unsigned short* __restrict__ xb, unsigned short* __restrict__ wp,
                       float* __restrict__ biasp) {
  int b = blockIdx.x;
  int t = threadIdx.x;
  if (b < 4096) {
    int i = b * 256 + t;  // 8 elems per thread
    const float4* x4 = (const float4*)x;
    float4 a = x4[i * 2], c = x4[i * 2 + 1];
    uint4 o;
    o.x = f2bf(a.x) | (f2bf(a.y) << 16);
    o.y = f2bf(a.z) | (f2bf(a.w) << 16);
    o.z = f2bf(c.x) | (f2bf(c.y) << 16);
    o.w = f2bf(c.z) | (f2bf(c.w) << 16);
    ((uint4*)xb)[i] = o;
  } else {
    int o = b - 4096;  // pooled feature index
    int r0 = ((o >> 5) << 7) + ((o & 31) << 1);
    const float4* W4 = (const float4*)W;
    float4 w0 = W4[(r0) * 256 + t];
    float4 w1 = W4[(r0 + 1) * 256 + t];
    float4 w2 = W4[(r0 + 64) * 256 + t];
    float4 w3 = W4[(r0 + 65) * 256 + t];
    float ax = 0.25f * (w0.x + w1.x + w2.x + w3.x);
    float ay = 0.25f * (w0.y + w1.y + w2.y + w3.y);
    float az = 0.25f * (w0.z + w1.z + w2.z + w3.z);
    float aw = 0.25f * (w0.w + w1.w + w2.w + w3.w);
    uint2 pk;
    pk.x = f2bf(ax) | (f2bf(ay) << 16);
    pk.y = f2bf(az) | (f2bf(aw) << 16);
    ((uint2*)wp)[o * 256 + t] = pk;
    if (t == 0)
      biasp[o] = 0.25f * (bias[r0] + bias[r0 + 1] + bias[r0 + 64] + bias[r0 + 65]);
  }
}

// ---- kernel 2: GEMM 8192x1024x1024 bf16 MFMA; 8 waves, dbuf, counted vmcnt ----
__global__ __launch_bounds__(512) void k_gemm(
    const unsigned short* __restrict__ xb, const unsigned short* __restrict__ wp,
    const float* __restrict__ biasp, const float* __restrict__ y,
    float* __restrict__ out, _Float16* __restrict__ ph,
    float* __restrict__ partials, int use16) {
  // buf in {0,1}: As(buf)=smem+buf*32768 (16KB), Bs(buf)=+16384
  __shared__ char smem[65536];

  int bid = blockIdx.x;
  // XCD swizzle: nwg=512 = 8*64, bijective
  int wg = (bid & 7) * 64 + (bid >> 3);
  int bm0 = (wg >> 3) * BM;
  int bn0 = (wg & 7) * BN;

  int tid = threadIdx.x;
  int lane = tid & 63;
  int wid = tid >> 6;               // 0..7
  int wr = wid >> 1, wc = wid & 1;  // wave tile 32x64: rows wr*32, cols wc*64

  f32x4 acc[2][4];
#pragma unroll
  for (int i = 0; i < 2; i++)
#pragma unroll
    for (int j = 0; j < 4; j++) acc[i][j] = (f32x4)0.0f;

  // staging: 512 threads x 16B = 8KB/call; A tile (16KB) = 2 calls, B = 2.
  // LDS dest linear (wave-uniform base + lane*16); SOURCE column chunk
  // pre-swizzled by (lane&7)^(lane>>3) — both-sides involution with the read.
  // row = tid>>3 (0..63), so row&7 == lane>>3 as before.
  int srow = tid >> 3;
  int scol = (((lane & 7) ^ (lane >> 3)) << 3);
  const unsigned short* aSrc = xb + (size_t)(bm0 + srow) * KDIM + scol;
  const unsigned short* bSrc = wp + (size_t)(bn0 + srow) * KDIM + scol;
  int ldsOff = wid * 1024;

  // read addressing: fragment row r has r&7 == lane&7; byte col =
  // (kk*64 + (lane>>4)*16) ^ ((lane&7)<<4)
  int rbase = (lane & 15) * 128;
  int xorv = (lane & 7) << 4;
  int cb0 = (((lane >> 4) * 16)) ^ xorv;
  int cb1 = ((64 + (lane >> 4) * 16)) ^ xorv;

#define STAGE(buf, ks)                                                         \
  {                                                                            \
    int k0 = (ks) * BK;                                                        \
    char* ab = smem + (buf) * 32768 + ldsOff;                                  \
    char* bb = smem + (buf) * 32768 + 16384 + ldsOff;                          \
    _Pragma("unroll")                                                          \
    for (int i = 0; i < 2; ++i)                                                \
      gload_lds16(aSrc + (size_t)i * 64 * KDIM + k0, ab + i * 8192);           \
    _Pragma("unroll")                                                          \
    for (int i = 0; i < 2; ++i)                                                \
      gload_lds16(bSrc + (size_t)i * 64 * KDIM + k0, bb + i * 8192);           \
  }

  STAGE(0, 0);
  for (int ks = 0; ks < 16; ++ks) {
    int cur = ks & 1;
    if (ks < 15) {
      STAGE(cur ^ 1, ks + 1);
      asm volatile("s_waitcnt vmcnt(4)" ::: "memory");
    } else {
      asm volatile("s_waitcnt vmcnt(0)" ::: "memory");
    }
    __builtin_amdgcn_s_barrier();
    asm volatile("" ::: "memory");
    const char* Ab = smem + cur * 32768;
    const char* Bb = Ab + 16384;
#pragma unroll
    for (int kk = 0; kk < 2; ++kk) {
      int cb = kk ? cb1 : cb0;
      bf16x8 af[2], bfr[4];
#pragma unroll
      for (int mi = 0; mi < 2; ++mi)
        af[mi] = *(const bf16x8*)(Ab + (wr * 32 + mi * 16) * 128 + rbase + cb);
#pragma unroll
      for (int ni = 0; ni < 4; ++ni)
        bfr[ni] = *(const bf16x8*)(Bb + (wc * 64 + ni * 16) * 128 + rbase + cb);
#pragma unroll
      for (int mi = 0; mi < 2; ++mi)
#pragma unroll
        for (int ni = 0; ni < 4; ++ni)
          acc[mi][ni] = __builtin_amdgcn_mfma_f32_16x16x32_bf16(af[mi], bfr[ni], acc[mi][ni], 0, 0, 0);
    }
    asm volatile("" ::: "memory");
    __builtin_amdgcn_s_barrier();
  }

  // epilogue: add pooled bias + pooled y, write intermediate, block sum
  const float2* y2 = (const float2*)y;
  float tsum = 0.f;
  int r_l = (lane >> 4) * 4;
  int c_l = lane & 15;
#pragma unroll
  for (int mi = 0; mi < 2; ++mi) {
#pragma unroll
    for (int ni = 0; ni < 4; ++ni) {
      int col = bn0 + wc * 64 + ni * 16 + c_l;  // pooled feature o
      float bp = biasp[col];
      int y2base = ((col >> 5) << 6) + (col & 31);
#pragma unroll
      for (int j = 0; j < 4; ++j) {
        int row = bm0 + wr * 32 + mi * 16 + r_l + j;  // batch b
        float2 u = y2[(size_t)row * 2048 + y2base];
        float2 v = y2[(size_t)row * 2048 + y2base + 32];
        float val = acc[mi][ni][j] + bp + 0.25f * (u.x + u.y + v.x + v.y);
        size_t idx = (size_t)row * NP + col;
        if (use16) ph[idx] = (_Float16)val;
        else out[idx] = val;
        tsum += val;
      }
    }
  }
#pragma unroll
  for (int off = 32; off > 0; off >>= 1) tsum += __shfl_down(tsum, off);
  float* sm = (float*)smem;
  __syncthreads();
  if (lane == 0) sm[wid] = tsum;
  __syncthreads();
  if (tid == 0)
    partials[bid] = ((sm[0] + sm[1]) + (sm[2] + sm[3])) +
                    ((sm[4] + sm[5]) + (sm[6] + sm[7]));
}

// ---- kernel 3: redundant per-block reduce of 512 partials; scale to f32 out ----
__global__ void k_norm(float* __restrict__ out, const _Float16* __restrict__ ph,
                       const float* __restrict__ partials, int use16) {
  __shared__ float s[256];
  int t = threadIdx.x;
  s[t] = partials[t] + partials[t + 256];
  __syncthreads();
#pragma unroll
  for (int off = 128; off > 0; off >>= 1) {
    if (t < off) s[t] += s[t + off];
    __syncthreads();
  }
  float inv = 8388608.0f / s[0];  // (B*NP)/total
  int i = blockIdx.x * 256 + t;   // float4 index
  float4* o4 = (float4*)out;
  if (use16) {
    f16x4 hv = ((const f16x4*)ph)[i];
    float4 v;
    v.x = (float)hv[0] * inv;
    v.y = (float)hv[1] * inv;
    v.z = (float)hv[2] * inv;
    v.w = (float)hv[3] * inv;
    o4[i] = v;
  } else {
    float4 v = o4[i];
    v.x *= inv; v.y *= inv; v.z *= inv; v.w *= inv;
    o4[i] = v;
  }
}

extern "C" void kernel_launch(void* const* d_in, const int* in_sizes, int n_in,
                              void* d_out, int out_size, void* d_ws, size_t ws_size,
                              hipStream_t stream) {
  (void)in_sizes; (void)n_in; (void)out_size;
  const float* x = (const float*)d_in[0];
  const float* y = (const float*)d_in[1];
  const float* W = (const float*)d_in[2];
  const float* bias = (const float*)d_in[3];
  float* out = (float*)d_out;

  char* ws = (char*)d_ws;
  unsigned short* xb = (unsigned short*)(ws);                 // 16 MiB
  unsigned short* wp = (unsigned short*)(ws + 16777216);      // 2 MiB
  float* biasp = (float*)(ws + 16777216 + 2097152);           // 4 KiB
  float* partials = (float*)(ws + 16777216 + 2097152 + 4096); // 2 KiB
  _Float16* ph = (_Float16*)(ws + 20971520);                  // 16 MiB (f16 intermediate)
  int use16 = (ws_size >= (size_t)20971520 + 16777216) ? 1 : 0;

  hipLaunchKernelGGL(k_prep, dim3(5120), dim3(256), 0, stream, x, W, bias, xb, wp, biasp);
  hipLaunchKernelGGL(k_gemm, dim3(512), dim3(512), 0, stream, xb, wp, biasp, y, out, ph, partials, use16);
  hipLaunchKernelGGL(k_norm, dim3(8192), dim3(256), 0, stream, out, ph, partials, use16);
}

// Round 9
// 57.841 us; speedup vs baseline: 1.2110x; 1.0741x over previous
//
#include <hip/hip_runtime.h>
#include <stdint.h>

// pooled[b,o] = x[b,:] . Wp[o,:] + biasp[o] + 0.25*(y[b,n0]+y[b,n0+1]+y[b,n0+64]+y[b,n0+65])
//   o = p*32+q, n0 = 128p+2q; Wp = 2x2-pooled W rows. out = pooled / mean(pooled).
// 3 dispatches: prep -> gemm (128x128, 8 waves, dbuf LDS, counted vmcnt, XOR
// swizzle; y-reads interleaved into the K-loop via asm dwordx2, rotating
// 3-slot buffer, lag-2 consume folded directly into acc) -> norm.

#define KDIM 1024
#define NP   1024
#define BM 128
#define BN 128
#define BK 64

typedef __bf16 bf16x8 __attribute__((ext_vector_type(8)));
typedef float f32x4 __attribute__((ext_vector_type(4)));
typedef _Float16 f16x4 __attribute__((ext_vector_type(4)));

__device__ __forceinline__ unsigned f2bf(float f) {
  union { float f; unsigned u; } v; v.f = f;
  unsigned r = v.u + 0x7fffu + ((v.u >> 16) & 1u);  // RNE
  return r >> 16;
}

__device__ __forceinline__ void gload_lds16(const void* g, void* l) {
  __builtin_amdgcn_global_load_lds(
      (const __attribute__((address_space(1))) void*)g,
      (__attribute__((address_space(3))) void*)l, 16, 0, 0);
}

// ---- kernel 1 (merged prep): x fp32->bf16 (blocks 0..4095), pool W+bias ----
__global__ void k_prep(const float* __restrict__ x, const float* __restrict__ W,
                       const float* __restrict__ bias,
                       unsigned short* __restrict__ xb, unsigned short* __restrict__ wp,
                       float* __restrict__ biasp) {
  int b = blockIdx.x;
  int t = threadIdx.x;
  if (b < 4096) {
    int i = b * 256 + t;  // 8 elems per thread
    const float4* x4 = (const float4*)x;
    float4 a = x4[i * 2], c = x4[i * 2 + 1];
    uint4 o;
    o.x = f2bf(a.x) | (f2bf(a.y) << 16);
    o.y = f2bf(a.z) | (f2bf(a.w) << 16);
    o.z = f2bf(c.x) | (f2bf(c.y) << 16);
    o.w = f2bf(c.z) | (f2bf(c.w) << 16);
    ((uint4*)xb)[i] = o;
  } else {
    int o = b - 4096;  // pooled feature index
    int r0 = ((o >> 5) << 7) + ((o & 31) << 1);
    const float4* W4 = (const float4*)W;
    float4 w0 = W4[(r0) * 256 + t];
    float4 w1 = W4[(r0 + 1) * 256 + t];
    float4 w2 = W4[(r0 + 64) * 256 + t];
    float4 w3 = W4[(r0 + 65) * 256 + t];
    float ax = 0.25f * (w0.x + w1.x + w2.x + w3.x);
    float ay = 0.25f * (w0.y + w1.y + w2.y + w3.y);
    float az = 0.25f * (w0.z + w1.z + w2.z + w3.z);
    float aw = 0.25f * (w0.w + w1.w + w2.w + w3.w);
    uint2 pk;
    pk.x = f2bf(ax) | (f2bf(ay) << 16);
    pk.y = f2bf(az) | (f2bf(aw) << 16);
    ((uint2*)wp)[o * 256 + t] = pk;
    if (t == 0)
      biasp[o] = 0.25f * (bias[r0] + bias[r0 + 1] + bias[r0 + 64] + bias[r0 + 65]);
  }
}

// ---- kernel 2: GEMM with y-reads interleaved into the K-loop ----
__global__ __launch_bounds__(512, 4) void k_gemm(
    const unsigned short* __restrict__ xb, const unsigned short* __restrict__ wp,
    const float* __restrict__ biasp, const float* __restrict__ y,
    float* __restrict__ out, _Float16* __restrict__ ph,
    float* __restrict__ partials, int use16) {
  // buf in {0,1}: As(buf)=smem+buf*32768 (16KB), Bs(buf)=+16384
  __shared__ char smem[65536];

  int bid = blockIdx.x;
  int wg = (bid & 7) * 64 + (bid >> 3);  // XCD swizzle, 512 = 8*64 bijective
  int bm0 = (wg >> 3) * BM;
  int bn0 = (wg & 7) * BN;

  int tid = threadIdx.x;
  int lane = tid & 63;
  int wid = tid >> 6;               // 0..7
  int wr = wid >> 1, wc = wid & 1;  // wave tile 32x64

  f32x4 acc[2][4];
#pragma unroll
  for (int i = 0; i < 2; i++)
#pragma unroll
    for (int j = 0; j < 4; j++) acc[i][j] = (f32x4)0.0f;

  // staging: 512 thr x 16B; A = 2 calls, B = 2 calls (4 vmcnt events/STAGE).
  int srow = tid >> 3;
  int scol = (((lane & 7) ^ (lane >> 3)) << 3);
  const unsigned short* aSrc = xb + (size_t)(bm0 + srow) * KDIM + scol;
  const unsigned short* bSrc = wp + (size_t)(bn0 + srow) * KDIM + scol;
  int ldsOff = wid * 1024;

  int rbase = (lane & 15) * 128;
  int xorv = (lane & 7) << 4;
  int cb0 = (((lane >> 4) * 16)) ^ xorv;
  int cb1 = ((64 + (lane >> 4) * 16)) ^ xorv;

  // y interleave setup. output idx q = mi*16+ni*4+j (mi<2,ni<4,j<4);
  // phase p loads q=2p,2p+1 (4 dwordx2), consumed at lag 2 into acc directly.
  const float2* y2 = (const float2*)y;
  int r_l = (lane >> 4) * 4;
  int c_l = lane & 15;
  int yrow0 = bm0 + wr * 32 + r_l;
  int yb[4];
#pragma unroll
  for (int ni = 0; ni < 4; ++ni) {
    int col = bn0 + wc * 64 + ni * 16 + c_l;
    yb[ni] = ((col >> 5) << 6) + (col & 31);
  }
  float2 yin[3][4];  // rotating 3-slot window

#define STAGE(buf, ks)                                                         \
  {                                                                            \
    int k0 = (ks) * BK;                                                        \
    char* ab = smem + (buf) * 32768 + ldsOff;                                  \
    char* bb = smem + (buf) * 32768 + 16384 + ldsOff;                          \
    _Pragma("unroll")                                                          \
    for (int i = 0; i < 2; ++i)                                                \
      gload_lds16(aSrc + (size_t)i * 64 * KDIM + k0, ab + i * 8192);           \
    _Pragma("unroll")                                                          \
    for (int i = 0; i < 2; ++i)                                                \
      gload_lds16(bSrc + (size_t)i * 64 * KDIM + k0, bb + i * 8192);           \
  }

#define YLD(p, s, q)                                                           \
  {                                                                            \
    const float2* pp = y2 +                                                    \
        (size_t)(yrow0 + (((q) >> 4) * 16) + ((q) & 3)) * 2048 +               \
        yb[((q) >> 2) & 3];                                                    \
    asm volatile("global_load_dwordx2 %0, %1, off"                             \
                 : "=v"(yin[(p) % 3][s]) : "v"(pp) : "memory");                \
    asm volatile("global_load_dwordx2 %0, %1, off offset:256"                  \
                 : "=v"(yin[(p) % 3][(s) + 1]) : "v"(pp) : "memory");          \
  }
#define YLOAD(p) { YLD(p, 0, 2 * (p)) YLD(p, 2, 2 * (p) + 1) }
// consume phase p's y straight into acc (q=2p, 2p+1); all indices constant.
#define YCONS(p)                                                               \
  {                                                                            \
    acc[(2 * (p)) >> 4][((2 * (p)) >> 2) & 3][(2 * (p)) & 3] +=                \
        0.25f * ((yin[(p) % 3][0].x + yin[(p) % 3][0].y) +                     \
                 (yin[(p) % 3][1].x + yin[(p) % 3][1].y));                     \
    acc[(2 * (p) + 1) >> 4][((2 * (p) + 1) >> 2) & 3][(2 * (p) + 1) & 3] +=    \
        0.25f * ((yin[(p) % 3][2].x + yin[(p) % 3][2].y) +                     \
                 (yin[(p) % 3][3].x + yin[(p) % 3][3].y));                     \
  }

#define COMPUTE(cur)                                                           \
  {                                                                            \
    const char* Ab = smem + (cur) * 32768;                                     \
    const char* Bb = Ab + 16384;                                               \
    _Pragma("unroll")                                                          \
    for (int kk = 0; kk < 2; ++kk) {                                           \
      int cb = kk ? cb1 : cb0;                                                 \
      bf16x8 af[2], bfr[4];                                                    \
      _Pragma("unroll")                                                        \
      for (int mi = 0; mi < 2; ++mi)                                           \
        af[mi] = *(const bf16x8*)(Ab + (wr * 32 + mi * 16) * 128 + rbase + cb);\
      _Pragma("unroll")                                                        \
      for (int ni = 0; ni < 4; ++ni)                                           \
        bfr[ni] = *(const bf16x8*)(Bb + (wc * 64 + ni * 16) * 128 + rbase + cb);\
      _Pragma("unroll")                                                        \
      for (int mi = 0; mi < 2; ++mi)                                           \
        _Pragma("unroll")                                                      \
        for (int ni = 0; ni < 4; ++ni)                                         \
          acc[mi][ni] = __builtin_amdgcn_mfma_f32_16x16x32_bf16(               \
              af[mi], bfr[ni], acc[mi][ni], 0, 0, 0);                          \
    }                                                                          \
  }

  // per iter issue order [STAGE(4), Y(4)]; in-order retirement means
  // vmcnt(12) (= newest Y_i, S_{i+1}, Y_{i-1}) guarantees S_i AND Y_{i-2}
  // retired. sched_barrier(0) fences the register-only consume (rule #18).
#define KITER(ks, WAITSTR)                                                     \
  {                                                                            \
    if ((ks) < 15) STAGE(((ks) + 1) & 1, (ks) + 1);                            \
    YLOAD(ks);                                                                 \
    asm volatile(WAITSTR ::: "memory");                                        \
    __builtin_amdgcn_s_barrier();                                              \
    COMPUTE((ks) & 1);                                                         \
    __builtin_amdgcn_sched_barrier(0);                                         \
    if ((ks) >= 2) YCONS(((ks) >= 2 ? (ks) - 2 : 0));                          \
    asm volatile("" ::: "memory");                                             \
    __builtin_amdgcn_s_barrier();                                              \
  }

  STAGE(0, 0);
  KITER(0,  "s_waitcnt vmcnt(8)")
  KITER(1,  "s_waitcnt vmcnt(12)")
  KITER(2,  "s_waitcnt vmcnt(12)")
  KITER(3,  "s_waitcnt vmcnt(12)")
  KITER(4,  "s_waitcnt vmcnt(12)")
  KITER(5,  "s_waitcnt vmcnt(12)")
  KITER(6,  "s_waitcnt vmcnt(12)")
  KITER(7,  "s_waitcnt vmcnt(12)")
  KITER(8,  "s_waitcnt vmcnt(12)")
  KITER(9,  "s_waitcnt vmcnt(12)")
  KITER(10, "s_waitcnt vmcnt(12)")
  KITER(11, "s_waitcnt vmcnt(12)")
  KITER(12, "s_waitcnt vmcnt(12)")
  KITER(13, "s_waitcnt vmcnt(12)")
  KITER(14, "s_waitcnt vmcnt(12)")
  KITER(15, "s_waitcnt vmcnt(0)")
  __builtin_amdgcn_sched_barrier(0);
  YCONS(14);
  YCONS(15);

  // epilogue: acc already holds gemm + pooled y; add bias, store, block sum
  float tsum = 0.f;
  float bpv[4];
#pragma unroll
  for (int ni = 0; ni < 4; ++ni) bpv[ni] = biasp[bn0 + wc * 64 + ni * 16 + c_l];
#pragma unroll
  for (int mi = 0; mi < 2; ++mi) {
#pragma unroll
    for (int ni = 0; ni < 4; ++ni) {
      int col = bn0 + wc * 64 + ni * 16 + c_l;
#pragma unroll
      for (int j = 0; j < 4; ++j) {
        int row = bm0 + wr * 32 + mi * 16 + r_l + j;
        float val = acc[mi][ni][j] + bpv[ni];
        size_t o = (size_t)row * NP + col;
        if (use16) ph[o] = (_Float16)val;
        else out[o] = val;
        tsum += val;
      }
    }
  }
#pragma unroll
  for (int off = 32; off > 0; off >>= 1) tsum += __shfl_down(tsum, off);
  float* sm = (float*)smem;
  __syncthreads();
  if (lane == 0) sm[wid] = tsum;
  __syncthreads();
  if (tid == 0)
    partials[bid] = ((sm[0] + sm[1]) + (sm[2] + sm[3])) +
                    ((sm[4] + sm[5]) + (sm[6] + sm[7]));
}

// ---- kernel 3: redundant per-block reduce of 512 partials; scale to f32 out ----
__global__ void k_norm(float* __restrict__ out, const _Float16* __restrict__ ph,
                       const float* __restrict__ partials, int use16) {
  __shared__ float s[256];
  int t = threadIdx.x;
  s[t] = partials[t] + partials[t + 256];
  __syncthreads();
#pragma unroll
  for (int off = 128; off > 0; off >>= 1) {
    if (t < off) s[t] += s[t + off];
    __syncthreads();
  }
  float inv = 8388608.0f / s[0];  // (B*NP)/total
  int i = blockIdx.x * 256 + t;   // float4 index
  float4* o4 = (float4*)out;
  if (use16) {
    f16x4 hv = ((const f16x4*)ph)[i];
    float4 v;
    v.x = (float)hv[0] * inv;
    v.y = (float)hv[1] * inv;
    v.z = (float)hv[2] * inv;
    v.w = (float)hv[3] * inv;
    o4[i] = v;
  } else {
    float4 v = o4[i];
    v.x *= inv; v.y *= inv; v.z *= inv; v.w *= inv;
    o4[i] = v;
  }
}

extern "C" void kernel_launch(void* const* d_in, const int* in_sizes, int n_in,
                              void* d_out, int out_size, void* d_ws, size_t ws_size,
                              hipStream_t stream) {
  (void)in_sizes; (void)n_in; (void)out_size;
  const float* x = (const float*)d_in[0];
  const float* y = (const float*)d_in[1];
  const float* W = (const float*)d_in[2];
  const float* bias = (const float*)d_in[3];
  float* out = (float*)d_out;

  char* ws = (char*)d_ws;
  unsigned short* xb = (unsigned short*)(ws);                 // 16 MiB
  unsigned short* wp = (unsigned short*)(ws + 16777216);      // 2 MiB
  float* biasp = (float*)(ws + 16777216 + 2097152);           // 4 KiB
  float* partials = (float*)(ws + 16777216 + 2097152 + 4096); // 2 KiB
  _Float16* ph = (_Float16*)(ws + 20971520);                  // 16 MiB
  int use16 = (ws_size >= (size_t)20971520 + 16777216) ? 1 : 0;

  hipLaunchKernelGGL(k_prep, dim3(5120), dim3(256), 0, stream, x, W, bias, xb, wp, biasp);
  hipLaunchKernelGGL(k_gemm, dim3(512), dim3(512), 0, stream, xb, wp, biasp, y, out, ph, partials, use16);
  hipLaunchKernelGGL(k_norm, dim3(8192), dim3(256), 0, stream, out, ph, partials, use16);
}